// Round 1
// baseline (778.342 us; speedup 1.0000x reference)
//
#include <hip/hip_runtime.h>
#include <math.h>

#define HIDDEN 1024
#define INTER  1408
#define NEXP   8
#define NTOK   2048

// ---------------------------------------------------------------------------
// Router: one wave per token. Computes 8 logits, softmax, top-2, renormalize,
// appends (token, weight) to per-expert lists via atomics.
// ---------------------------------------------------------------------------
__global__ __launch_bounds__(256) void router_kernel(
    const float* __restrict__ x, const float* __restrict__ rw,
    int* __restrict__ counts, int* __restrict__ tok_list,
    float* __restrict__ w_list)
{
  int wave = threadIdx.x >> 6;
  int lane = threadIdx.x & 63;
  int t = blockIdx.x * 4 + wave;
  if (t >= NTOK) return;
  const float* xt = x + (size_t)t * HIDDEN;
  float xr[16];
#pragma unroll
  for (int i = 0; i < 16; ++i) xr[i] = xt[lane + 64 * i];
  float logits[NEXP];
#pragma unroll
  for (int e = 0; e < NEXP; ++e) {
    const float* w = rw + e * HIDDEN;
    float acc = 0.f;
#pragma unroll
    for (int i = 0; i < 16; ++i) acc = fmaf(xr[i], w[lane + 64 * i], acc);
#pragma unroll
    for (int off = 32; off > 0; off >>= 1) acc += __shfl_xor(acc, off);
    logits[e] = acc;
  }
  if (lane == 0) {
    float mx = logits[0];
#pragma unroll
    for (int e = 1; e < NEXP; ++e) mx = fmaxf(mx, logits[e]);
    float p[NEXP];
#pragma unroll
    for (int e = 0; e < NEXP; ++e) p[e] = expf(logits[e] - mx);
    // top-2 (strict > keeps lowest index on ties, matching lax.top_k)
    int i0 = 0;
#pragma unroll
    for (int e = 1; e < NEXP; ++e) if (p[e] > p[i0]) i0 = e;
    int i1 = (i0 == 0) ? 1 : 0;
#pragma unroll
    for (int e = 0; e < NEXP; ++e) { if (e != i0 && p[e] > p[i1]) i1 = e; }
    float denom = p[i0] + p[i1];
    float w0 = p[i0] / denom;
    float w1 = p[i1] / denom;
    int pos0 = atomicAdd(&counts[i0], 1);
    tok_list[i0 * NTOK + pos0] = t;
    w_list[i0 * NTOK + pos0] = w0;
    int pos1 = atomicAdd(&counts[i1], 1);
    tok_list[i1 * NTOK + pos1] = t;
    w_list[i1 * NTOK + pos1] = w1;
  }
}

// ---------------------------------------------------------------------------
// Exclusive prefix over the 8 expert counts -> hbuf row bases.
// ---------------------------------------------------------------------------
__global__ void prefix_kernel(const int* __restrict__ counts, int* __restrict__ base)
{
  if (threadIdx.x == 0 && blockIdx.x == 0) {
    int s = 0;
    for (int e = 0; e < NEXP; ++e) { base[e] = s; s += counts[e]; }
  }
}

// ---------------------------------------------------------------------------
// Phase A: per expert, H = silu(X@Wg) * (X@Wu), grouped-token GEMM.
// 64x64 tile, 256 threads, 4x4 micro-tile per thread, K-step 16.
// ---------------------------------------------------------------------------
__global__ __launch_bounds__(256) void gateup_kernel(
    const float* __restrict__ x, const float* __restrict__ wg,
    const float* __restrict__ wu,
    const int* __restrict__ counts, const int* __restrict__ base,
    const int* __restrict__ tok_list, float* __restrict__ hbuf)
{
  int e = blockIdx.z;
  int cnt = counts[e];
  int m0 = blockIdx.y * 64;
  if (m0 >= cnt) return;
  int n0 = blockIdx.x * 64;

  __shared__ float As[16][64];   // [k][m]
  __shared__ float Bg[16][64];   // [k][n]
  __shared__ float Bu[16][64];
  __shared__ int toks[64];

  int tid = threadIdx.x;
  if (tid < 64) {
    int r = m0 + tid;
    toks[tid] = tok_list[e * NTOK + (r < cnt ? r : cnt - 1)];
  }
  __syncthreads();

  int tx = tid & 15, ty = tid >> 4;
  float ag[4][4] = {{0.f}}, au[4][4] = {{0.f}};
  const float* wge = wg + (size_t)e * HIDDEN * INTER;
  const float* wue = wu + (size_t)e * HIDDEN * INTER;

  int arow = tid >> 2, acol = (tid & 3) * 4;
  int brow = tid >> 4, bcol = (tid & 15) * 4;
  const float* xrow = x + (size_t)toks[arow] * HIDDEN;

  for (int k0 = 0; k0 < HIDDEN; k0 += 16) {
    float4 av = *(const float4*)(xrow + k0 + acol);
    float4 gv = *(const float4*)(wge + (size_t)(k0 + brow) * INTER + n0 + bcol);
    float4 uv = *(const float4*)(wue + (size_t)(k0 + brow) * INTER + n0 + bcol);
    As[acol + 0][arow] = av.x;
    As[acol + 1][arow] = av.y;
    As[acol + 2][arow] = av.z;
    As[acol + 3][arow] = av.w;
    *(float4*)&Bg[brow][bcol] = gv;
    *(float4*)&Bu[brow][bcol] = uv;
    __syncthreads();
#pragma unroll
    for (int kk = 0; kk < 16; ++kk) {
      float4 a  = *(const float4*)&As[kk][ty * 4];
      float4 bg = *(const float4*)&Bg[kk][tx * 4];
      float4 bu = *(const float4*)&Bu[kk][tx * 4];
      float aa[4] = {a.x, a.y, a.z, a.w};
      float gg[4] = {bg.x, bg.y, bg.z, bg.w};
      float uu[4] = {bu.x, bu.y, bu.z, bu.w};
#pragma unroll
      for (int i = 0; i < 4; ++i)
#pragma unroll
        for (int j = 0; j < 4; ++j) {
          ag[i][j] = fmaf(aa[i], gg[j], ag[i][j]);
          au[i][j] = fmaf(aa[i], uu[j], au[i][j]);
        }
    }
    __syncthreads();
  }

  int hb = base[e];
#pragma unroll
  for (int i = 0; i < 4; ++i) {
    int r = m0 + ty * 4 + i;
    if (r < cnt) {
      float4 hv;
      float g, u;
      g = ag[i][0]; u = au[i][0]; hv.x = (g / (1.f + __expf(-g))) * u;
      g = ag[i][1]; u = au[i][1]; hv.y = (g / (1.f + __expf(-g))) * u;
      g = ag[i][2]; u = au[i][2]; hv.z = (g / (1.f + __expf(-g))) * u;
      g = ag[i][3]; u = au[i][3]; hv.w = (g / (1.f + __expf(-g))) * u;
      *(float4*)(hbuf + (size_t)(hb + r) * INTER + n0 + tx * 4) = hv;
    }
  }
}

// ---------------------------------------------------------------------------
// Phase B: per expert, Y = H @ Wd, scaled by router weight, atomicAdd into out.
// Each out element receives exactly 2 adds (one per routed expert) -> sum is
// order-independent (2-term fp add is commutative), so result is deterministic.
// ---------------------------------------------------------------------------
__global__ __launch_bounds__(256) void down_kernel(
    const float* __restrict__ hbuf, const float* __restrict__ wd,
    const int* __restrict__ counts, const int* __restrict__ base,
    const int* __restrict__ tok_list, const float* __restrict__ w_list,
    float* __restrict__ out)
{
  int e = blockIdx.z;
  int cnt = counts[e];
  int m0 = blockIdx.y * 64;
  if (m0 >= cnt) return;
  int n0 = blockIdx.x * 64;

  __shared__ float As[16][64];
  __shared__ float Bs[16][64];

  int tid = threadIdx.x;
  int tx = tid & 15, ty = tid >> 4;
  float acc[4][4] = {{0.f}};
  int hb = base[e];
  const float* wde = wd + (size_t)e * INTER * HIDDEN;

  int arow = tid >> 2, acol = (tid & 3) * 4;
  int brow = tid >> 4, bcol = (tid & 15) * 4;
  int arow_c = (m0 + arow < cnt) ? (m0 + arow) : (cnt - 1);
  const float* hrow = hbuf + (size_t)(hb + arow_c) * INTER;

  for (int k0 = 0; k0 < INTER; k0 += 16) {
    float4 av = *(const float4*)(hrow + k0 + acol);
    float4 bv = *(const float4*)(wde + (size_t)(k0 + brow) * HIDDEN + n0 + bcol);
    As[acol + 0][arow] = av.x;
    As[acol + 1][arow] = av.y;
    As[acol + 2][arow] = av.z;
    As[acol + 3][arow] = av.w;
    *(float4*)&Bs[brow][bcol] = bv;
    __syncthreads();
#pragma unroll
    for (int kk = 0; kk < 16; ++kk) {
      float4 a = *(const float4*)&As[kk][ty * 4];
      float4 b = *(const float4*)&Bs[kk][tx * 4];
      float aa[4] = {a.x, a.y, a.z, a.w};
      float bb[4] = {b.x, b.y, b.z, b.w};
#pragma unroll
      for (int i = 0; i < 4; ++i)
#pragma unroll
        for (int j = 0; j < 4; ++j)
          acc[i][j] = fmaf(aa[i], bb[j], acc[i][j]);
    }
    __syncthreads();
  }

#pragma unroll
  for (int i = 0; i < 4; ++i) {
    int r = m0 + ty * 4 + i;
    if (r < cnt) {
      float wgt = w_list[e * NTOK + r];
      int tok = tok_list[e * NTOK + r];
      float* op = out + (size_t)tok * HIDDEN + n0 + tx * 4;
#pragma unroll
      for (int j = 0; j < 4; ++j)
        atomicAdd(op + j, acc[i][j] * wgt);
    }
  }
}

// ---------------------------------------------------------------------------
// ws layout:
//   [0    ..   32) int counts[8]
//   [32   ..   64) int base[8]
//   [64   ..64+64K) int tok_list[8][2048]
//   [+64K ..+128K) float w_list[8][2048]
//   [131136 .. +23.1MB) float hbuf[4096][1408]
// total ~23.2 MB
// ---------------------------------------------------------------------------
extern "C" void kernel_launch(void* const* d_in, const int* in_sizes, int n_in,
                              void* d_out, int out_size, void* d_ws, size_t ws_size,
                              hipStream_t stream)
{
  const float* x  = (const float*)d_in[0];
  const float* rw = (const float*)d_in[1];
  const float* wg = (const float*)d_in[2];
  const float* wu = (const float*)d_in[3];
  const float* wd = (const float*)d_in[4];
  float* out = (float*)d_out;

  char* ws = (char*)d_ws;
  int*   counts   = (int*)(ws);
  int*   base     = (int*)(ws + 32);
  int*   tok_list = (int*)(ws + 64);
  float* w_list   = (float*)(ws + 64 + NEXP * NTOK * 4);
  float* hbuf     = (float*)(ws + 64 + 2 * NEXP * NTOK * 4);

  hipMemsetAsync(ws, 0, 64, stream);                                  // counts+base
  hipMemsetAsync(out, 0, (size_t)out_size * sizeof(float), stream);   // accumulator

  router_kernel<<<NTOK / 4, 256, 0, stream>>>(x, rw, counts, tok_list, w_list);
  prefix_kernel<<<1, 64, 0, stream>>>(counts, base);

  dim3 gA(INTER / 64, NTOK / 64, NEXP);
  gateup_kernel<<<gA, 256, 0, stream>>>(x, wg, wu, counts, base, tok_list, hbuf);

  dim3 gB(HIDDEN / 64, NTOK / 64, NEXP);
  down_kernel<<<gB, 256, 0, stream>>>(hbuf, wd, counts, base, tok_list, w_list, out);
}

// Round 2
// 370.267 us; speedup vs baseline: 2.1021x; 2.1021x over previous
//
#include <hip/hip_runtime.h>
#include <math.h>

#define HIDDEN 1024
#define INTER  1408
#define NEXP   8
#define NTOK   2048

typedef short  s16x8 __attribute__((ext_vector_type(8)));   // 8 bf16 MFMA operand
typedef float  f32x4 __attribute__((ext_vector_type(4)));   // MFMA accumulator

static __device__ inline short f2b(float f) {
  union { float f; unsigned u; } v; v.f = f;
  unsigned u = v.u;
  unsigned r = (u + 0x7FFFu + ((u >> 16) & 1u)) >> 16;   // RNE
  return (short)r;
}

// ---------------------------------------------------------------------------
// Router: one wave per token, fp32 exact (top-k decisions must not flip).
// ---------------------------------------------------------------------------
__global__ __launch_bounds__(256) void router_kernel(
    const float* __restrict__ x, const float* __restrict__ rw,
    int* __restrict__ counts, int* __restrict__ tok_list,
    float* __restrict__ w_list)
{
  int wave = threadIdx.x >> 6;
  int lane = threadIdx.x & 63;
  int t = blockIdx.x * 4 + wave;
  if (t >= NTOK) return;
  const float* xt = x + (size_t)t * HIDDEN;
  float xr[16];
#pragma unroll
  for (int i = 0; i < 16; ++i) xr[i] = xt[lane + 64 * i];
  float logits[NEXP];
#pragma unroll
  for (int e = 0; e < NEXP; ++e) {
    const float* w = rw + e * HIDDEN;
    float acc = 0.f;
#pragma unroll
    for (int i = 0; i < 16; ++i) acc = fmaf(xr[i], w[lane + 64 * i], acc);
#pragma unroll
    for (int off = 32; off > 0; off >>= 1) acc += __shfl_xor(acc, off);
    logits[e] = acc;
  }
  if (lane == 0) {
    float mx = logits[0];
#pragma unroll
    for (int e = 1; e < NEXP; ++e) mx = fmaxf(mx, logits[e]);
    float p[NEXP];
#pragma unroll
    for (int e = 0; e < NEXP; ++e) p[e] = expf(logits[e] - mx);
    int i0 = 0;
#pragma unroll
    for (int e = 1; e < NEXP; ++e) if (p[e] > p[i0]) i0 = e;
    int i1 = (i0 == 0) ? 1 : 0;
#pragma unroll
    for (int e = 0; e < NEXP; ++e) { if (e != i0 && p[e] > p[i1]) i1 = e; }
    float denom = p[i0] + p[i1];
    int pos0 = atomicAdd(&counts[i0], 1);
    tok_list[i0 * NTOK + pos0] = t;
    w_list[i0 * NTOK + pos0] = p[i0] / denom;
    int pos1 = atomicAdd(&counts[i1], 1);
    tok_list[i1 * NTOK + pos1] = t;
    w_list[i1 * NTOK + pos1] = p[i1] / denom;
  }
}

__global__ void prefix_kernel(const int* __restrict__ counts, int* __restrict__ base)
{
  if (threadIdx.x == 0 && blockIdx.x == 0) {
    int s = 0;
    for (int e = 0; e < NEXP; ++e) { base[e] = s; s += counts[e]; }
  }
}

// ---------------------------------------------------------------------------
// x fp32 -> bf16 (same layout). 8 elems per thread.
// ---------------------------------------------------------------------------
__global__ __launch_bounds__(256) void convx_kernel(
    const float* __restrict__ x, short* __restrict__ xb)
{
  int i = blockIdx.x * 256 + threadIdx.x;
  const float4* p = (const float4*)x;
  float4 a = p[2 * i], b = p[2 * i + 1];
  s16x8 o;
  o[0] = f2b(a.x); o[1] = f2b(a.y); o[2] = f2b(a.z); o[3] = f2b(a.w);
  o[4] = f2b(b.x); o[5] = f2b(b.y); o[6] = f2b(b.z); o[7] = f2b(b.w);
  *(s16x8*)(xb + 8 * (size_t)i) = o;
}

// ---------------------------------------------------------------------------
// Transpose-convert: in fp32 [e][K][N] -> out bf16 [e][N][K]. 64x64 tiles.
// Makes the GEMM B-operand k-contiguous so fragments load as ds_read_b128.
// ---------------------------------------------------------------------------
__global__ __launch_bounds__(256) void tconv_kernel(
    const float* __restrict__ in, short* __restrict__ out, int K, int N)
{
  int e = blockIdx.z;
  const float* ie = in + (size_t)e * K * N;
  short* oe = out + (size_t)e * K * N;
  int k0 = blockIdx.y * 64, n0 = blockIdx.x * 64;
  __shared__ float t[64][65];
  int tid = threadIdx.x;
  int c4 = (tid & 15) * 4, r = tid >> 4;
#pragma unroll
  for (int p = 0; p < 4; ++p) {
    float4 v = *(const float4*)(ie + (size_t)(k0 + r + p * 16) * N + n0 + c4);
    t[r + p * 16][c4 + 0] = v.x;
    t[r + p * 16][c4 + 1] = v.y;
    t[r + p * 16][c4 + 2] = v.z;
    t[r + p * 16][c4 + 3] = v.w;
  }
  __syncthreads();
  int rn = tid >> 2, ck = (tid & 3) * 16;
  s16x8 o0, o1;
#pragma unroll
  for (int j = 0; j < 8; ++j) o0[j] = f2b(t[ck + j][rn]);
#pragma unroll
  for (int j = 0; j < 8; ++j) o1[j] = f2b(t[ck + 8 + j][rn]);
  short* op = oe + (size_t)(n0 + rn) * K + k0 + ck;
  *(s16x8*)(op) = o0;
  *(s16x8*)(op + 8) = o1;
}

// ---------------------------------------------------------------------------
// Phase A: H = silu(X@Wg) * (X@Wu), bf16 MFMA, 128x128 tile, 4 waves 2x2,
// each wave 4x4 grid of 16x16x32 MFMAs, BK=32. Gate+up share A staging.
// ---------------------------------------------------------------------------
__global__ __launch_bounds__(256, 2) void gateup_mfma(
    const short* __restrict__ xb, const short* __restrict__ wgT,
    const short* __restrict__ wuT,
    const int* __restrict__ counts, const int* __restrict__ base,
    const int* __restrict__ tok_list, short* __restrict__ hbuf)
{
  int e = blockIdx.z;
  int cnt = counts[e];
  int m0 = blockIdx.y * 128;
  if (m0 >= cnt) return;
  int n0 = blockIdx.x * 128;

  __shared__ short As[128 * 32];
  __shared__ short Bg[128 * 32];
  __shared__ short Bu[128 * 32];
  __shared__ int toks[128];

  int tid = threadIdx.x;
  if (tid < 128) {
    int r = m0 + tid;
    toks[tid] = tok_list[e * NTOK + (r < cnt ? r : cnt - 1)];
  }
  __syncthreads();

  int row = tid >> 1;          // 0..127
  int half = (tid & 1) * 16;   // element offset 0 / 16
  const short* aptr = xb + (size_t)toks[row] * HIDDEN + half;
  const short* gptr = wgT + ((size_t)e * INTER + n0 + row) * HIDDEN + half;
  const short* uptr = wuT + ((size_t)e * INTER + n0 + row) * HIDDEN + half;
  short* asw = &As[row * 32 + half];
  short* gsw = &Bg[row * 32 + half];
  short* usw = &Bu[row * 32 + half];

  int wv = tid >> 6, lane = tid & 63;
  int wm = wv & 1, wn = wv >> 1;
  int q = lane >> 4, ml = lane & 15;
  const short* ard = &As[(wm * 64 + ml) * 32 + q * 8];
  const short* grd = &Bg[(wn * 64 + ml) * 32 + q * 8];
  const short* urd = &Bu[(wn * 64 + ml) * 32 + q * 8];

  f32x4 accg[4][4], accu[4][4];
#pragma unroll
  for (int i = 0; i < 4; ++i)
#pragma unroll
    for (int j = 0; j < 4; ++j) { accg[i][j] = (f32x4)0.f; accu[i][j] = (f32x4)0.f; }

  for (int k0 = 0; k0 < HIDDEN; k0 += 32) {
    s16x8 a0 = *(const s16x8*)(aptr + k0);
    s16x8 a1 = *(const s16x8*)(aptr + k0 + 8);
    s16x8 g0 = *(const s16x8*)(gptr + k0);
    s16x8 g1 = *(const s16x8*)(gptr + k0 + 8);
    s16x8 u0 = *(const s16x8*)(uptr + k0);
    s16x8 u1 = *(const s16x8*)(uptr + k0 + 8);
    __syncthreads();   // previous iter's fragment reads done
    *(s16x8*)(asw) = a0; *(s16x8*)(asw + 8) = a1;
    *(s16x8*)(gsw) = g0; *(s16x8*)(gsw + 8) = g1;
    *(s16x8*)(usw) = u0; *(s16x8*)(usw + 8) = u1;
    __syncthreads();

    s16x8 af[4], gf[4], uf[4];
#pragma unroll
    for (int i = 0; i < 4; ++i) af[i] = *(const s16x8*)(ard + i * 16 * 32);
#pragma unroll
    for (int j = 0; j < 4; ++j) {
      gf[j] = *(const s16x8*)(grd + j * 16 * 32);
      uf[j] = *(const s16x8*)(urd + j * 16 * 32);
    }
#pragma unroll
    for (int i = 0; i < 4; ++i)
#pragma unroll
      for (int j = 0; j < 4; ++j) {
        accg[i][j] = __builtin_amdgcn_mfma_f32_16x16x32_bf16(af[i], gf[j], accg[i][j], 0, 0, 0);
        accu[i][j] = __builtin_amdgcn_mfma_f32_16x16x32_bf16(af[i], uf[j], accu[i][j], 0, 0, 0);
      }
  }

  int hb = base[e];
#pragma unroll
  for (int i = 0; i < 4; ++i)
#pragma unroll
    for (int ii = 0; ii < 4; ++ii) {
      int r = m0 + wm * 64 + i * 16 + q * 4 + ii;
      if (r < cnt) {
#pragma unroll
        for (int j = 0; j < 4; ++j) {
          int c = n0 + wn * 64 + j * 16 + ml;
          float g = accg[i][j][ii], u = accu[i][j][ii];
          float h = (g / (1.f + __expf(-g))) * u;
          hbuf[(size_t)(hb + r) * INTER + c] = f2b(h);
        }
      }
    }
}

// ---------------------------------------------------------------------------
// Phase B: Y = H @ Wd (bf16 MFMA), scale by router weight, atomicAdd to out.
// ---------------------------------------------------------------------------
__global__ __launch_bounds__(256, 2) void down_mfma(
    const short* __restrict__ hbuf, const short* __restrict__ wdT,
    const int* __restrict__ counts, const int* __restrict__ base,
    const int* __restrict__ tok_list, const float* __restrict__ w_list,
    float* __restrict__ out)
{
  int e = blockIdx.z;
  int cnt = counts[e];
  int m0 = blockIdx.y * 128;
  if (m0 >= cnt) return;
  int n0 = blockIdx.x * 128;

  __shared__ short As[128 * 32];
  __shared__ short Bs[128 * 32];

  int tid = threadIdx.x;
  int hb = base[e];

  int row = tid >> 1;
  int half = (tid & 1) * 16;
  int ar = m0 + row; if (ar >= cnt) ar = cnt - 1;
  const short* aptr = hbuf + (size_t)(hb + ar) * INTER + half;
  const short* bptr = wdT + ((size_t)e * HIDDEN + n0 + row) * INTER + half;
  short* asw = &As[row * 32 + half];
  short* bsw = &Bs[row * 32 + half];

  int wv = tid >> 6, lane = tid & 63;
  int wm = wv & 1, wn = wv >> 1;
  int q = lane >> 4, ml = lane & 15;
  const short* ard = &As[(wm * 64 + ml) * 32 + q * 8];
  const short* brd = &Bs[(wn * 64 + ml) * 32 + q * 8];

  f32x4 acc[4][4];
#pragma unroll
  for (int i = 0; i < 4; ++i)
#pragma unroll
    for (int j = 0; j < 4; ++j) acc[i][j] = (f32x4)0.f;

  for (int k0 = 0; k0 < INTER; k0 += 32) {
    s16x8 a0 = *(const s16x8*)(aptr + k0);
    s16x8 a1 = *(const s16x8*)(aptr + k0 + 8);
    s16x8 b0 = *(const s16x8*)(bptr + k0);
    s16x8 b1 = *(const s16x8*)(bptr + k0 + 8);
    __syncthreads();
    *(s16x8*)(asw) = a0; *(s16x8*)(asw + 8) = a1;
    *(s16x8*)(bsw) = b0; *(s16x8*)(bsw + 8) = b1;
    __syncthreads();

    s16x8 af[4], bf[4];
#pragma unroll
    for (int i = 0; i < 4; ++i) af[i] = *(const s16x8*)(ard + i * 16 * 32);
#pragma unroll
    for (int j = 0; j < 4; ++j) bf[j] = *(const s16x8*)(brd + j * 16 * 32);
#pragma unroll
    for (int i = 0; i < 4; ++i)
#pragma unroll
      for (int j = 0; j < 4; ++j)
        acc[i][j] = __builtin_amdgcn_mfma_f32_16x16x32_bf16(af[i], bf[j], acc[i][j], 0, 0, 0);
  }

#pragma unroll
  for (int i = 0; i < 4; ++i)
#pragma unroll
    for (int ii = 0; ii < 4; ++ii) {
      int r = m0 + wm * 64 + i * 16 + q * 4 + ii;
      if (r < cnt) {
        float wgt = w_list[e * NTOK + r];
        int tok = tok_list[e * NTOK + r];
        float* op = out + (size_t)tok * HIDDEN + n0 + wn * 64 + ml;
#pragma unroll
        for (int j = 0; j < 4; ++j)
          atomicAdd(op + j * 16, acc[i][j][ii] * wgt);
      }
    }
}

// ---------------------------------------------------------------------------
// ws layout (bytes):
//   0..32           counts[8]
//   32..64          base[8]
//   64..65600       tok_list[8][2048]
//   65600..131136   w_list[8][2048]
//   131136          xb   bf16 [2048][1024]            (4 MB)
//   +4194304        wgT  bf16 [8][1408][1024]         (23.07 MB)
//   +23068672       wuT  bf16 [8][1408][1024]
//   +23068672       wdT  bf16 [8][1024][1408]
//   +23068672       hbuf bf16 [4096][1408]            (11.5 MB)
//   total ~85.1 MB
// ---------------------------------------------------------------------------
extern "C" void kernel_launch(void* const* d_in, const int* in_sizes, int n_in,
                              void* d_out, int out_size, void* d_ws, size_t ws_size,
                              hipStream_t stream)
{
  const float* x  = (const float*)d_in[0];
  const float* rw = (const float*)d_in[1];
  const float* wg = (const float*)d_in[2];
  const float* wu = (const float*)d_in[3];
  const float* wd = (const float*)d_in[4];
  float* out = (float*)d_out;

  char* ws = (char*)d_ws;
  int*   counts   = (int*)(ws);
  int*   base     = (int*)(ws + 32);
  int*   tok_list = (int*)(ws + 64);
  float* w_list   = (float*)(ws + 64 + NEXP * NTOK * 4);
  size_t off = 64 + 2 * (size_t)NEXP * NTOK * 4;
  short* xb  = (short*)(ws + off);  off += (size_t)NTOK * HIDDEN * 2;
  short* wgT = (short*)(ws + off);  off += (size_t)NEXP * HIDDEN * INTER * 2;
  short* wuT = (short*)(ws + off);  off += (size_t)NEXP * HIDDEN * INTER * 2;
  short* wdT = (short*)(ws + off);  off += (size_t)NEXP * HIDDEN * INTER * 2;
  short* hbuf = (short*)(ws + off);

  hipMemsetAsync(ws, 0, 64, stream);
  hipMemsetAsync(out, 0, (size_t)out_size * sizeof(float), stream);

  convx_kernel<<<(NTOK * HIDDEN / 8) / 256, 256, 0, stream>>>(x, xb);
  {
    dim3 g(INTER / 64, HIDDEN / 64, NEXP);   // wg/wu: K=HIDDEN, N=INTER
    tconv_kernel<<<g, 256, 0, stream>>>(wg, wgT, HIDDEN, INTER);
    tconv_kernel<<<g, 256, 0, stream>>>(wu, wuT, HIDDEN, INTER);
  }
  {
    dim3 g(HIDDEN / 64, INTER / 64, NEXP);   // wd: K=INTER, N=HIDDEN
    tconv_kernel<<<g, 256, 0, stream>>>(wd, wdT, INTER, HIDDEN);
  }

  router_kernel<<<NTOK / 4, 256, 0, stream>>>(x, rw, counts, tok_list, w_list);
  prefix_kernel<<<1, 64, 0, stream>>>(counts, base);

  dim3 gA(INTER / 128, NTOK / 128, NEXP);
  gateup_mfma<<<gA, 256, 0, stream>>>(xb, wgT, wuT, counts, base, tok_list, hbuf);

  dim3 gB(HIDDEN / 128, NTOK / 128, NEXP);
  down_mfma<<<gB, 256, 0, stream>>>(hbuf, wdT, counts, base, tok_list, w_list, out);
}